// Round 3
// baseline (593.142 us; speedup 1.0000x reference)
//
#include <hip/hip_runtime.h>
#include <hip/hip_bf16.h>

typedef unsigned short ushort_t;
typedef __attribute__((ext_vector_type(8))) short short8;
typedef __attribute__((ext_vector_type(4))) short short4v;
typedef __attribute__((ext_vector_type(4))) float floatx4;

#define MFMA16(a, b, c) __builtin_amdgcn_mfma_f32_16x16x32_bf16(a, b, c, 0, 0, 0)

__device__ __forceinline__ float bf2f(ushort_t u) {
    unsigned int v = ((unsigned int)u) << 16;
    return __int_as_float((int)v);
}
__device__ __forceinline__ ushort_t f2bf(float f) {
    unsigned int x = (unsigned int)__float_as_int(f);
    unsigned int r = (x + 0x7FFFu + ((x >> 16) & 1u)) >> 16;
    return (ushort_t)r;
}
__device__ __forceinline__ floatx4 fma4(float a, floatx4 b, floatx4 c) {
    c[0] = fmaf(a, b[0], c[0]);
    c[1] = fmaf(a, b[1], c[1]);
    c[2] = fmaf(a, b[2], c[2]);
    c[3] = fmaf(a, b[3], c[3]);
    return c;
}

// ---------------------------------------------------------------- fp32 -> bf16 convert
__global__ __launch_bounds__(256) void k_cvt(const floatx4* __restrict__ src,
                                             short4v* __restrict__ dst, int n4) {
    int i = blockIdx.x * 256 + threadIdx.x;
    if (i < n4) {
        floatx4 v = src[i];
        short4v o;
        o[0] = (short)f2bf(v[0]);
        o[1] = (short)f2bf(v[1]);
        o[2] = (short)f2bf(v[2]);
        o[3] = (short)f2bf(v[3]);
        dst[i] = o;
    }
}

// ---------------------------------------------------------------- fp32 transpose -> bf16
__global__ __launch_bounds__(256) void k_transpose_cvt(const float* __restrict__ src,
                                                       ushort_t* __restrict__ dst, int R, int C) {
    __shared__ float t[32][33];
    int tx = threadIdx.x & 31, ty = threadIdx.x >> 5;
    int r0 = blockIdx.y * 32, c0 = blockIdx.x * 32;
    for (int y = ty; y < 32; y += 8) t[y][tx] = src[(r0 + y) * C + c0 + tx];
    __syncthreads();
    for (int y = ty; y < 32; y += 8) dst[(c0 + y) * R + r0 + tx] = f2bf(t[tx][y]);
}

// ---------------------------------------------------------------- K1: qkv = x @ w_qkv, scatter q/k/vT
__global__ __launch_bounds__(256) void k_qkv(const ushort_t* __restrict__ x,
                                             const ushort_t* __restrict__ wt,
                                             ushort_t* __restrict__ qs,
                                             ushort_t* __restrict__ ks,
                                             ushort_t* __restrict__ vt) {
    __shared__ __align__(16) ushort_t st[64 * 72];
    const int tid = threadIdx.x, lane = tid & 63, wv = tid >> 6;
    const int col = lane & 15, quad = lane >> 4;
    const int row0 = blockIdx.y * 64 + (wv >> 1) * 32;
    const int c0 = blockIdx.x * 64 + (wv & 1) * 32;
    const int which = blockIdx.x >> 3, hh = blockIdx.x & 7;
    const int brow0 = blockIdx.y * 64;
    const int bb = brow0 >> 11, n0 = brow0 & 2047;
    const int hidx = bb * 8 + hh;
    floatx4 acc[2][2];
#pragma unroll
    for (int i = 0; i < 2; i++)
#pragma unroll
        for (int j = 0; j < 2; j++) acc[i][j] = (floatx4){0.f, 0.f, 0.f, 0.f};
    for (int k0 = 0; k0 < 512; k0 += 32) {
        const int ko = k0 + quad * 8;
        short8 a0 = *(const short8*)&x[(row0 + col) * 512 + ko];
        short8 a1 = *(const short8*)&x[(row0 + 16 + col) * 512 + ko];
        short8 b0 = *(const short8*)&wt[(c0 + col) * 512 + ko];
        short8 b1 = *(const short8*)&wt[(c0 + 16 + col) * 512 + ko];
        acc[0][0] = MFMA16(a0, b0, acc[0][0]);
        acc[0][1] = MFMA16(a0, b1, acc[0][1]);
        acc[1][0] = MFMA16(a1, b0, acc[1][0]);
        acc[1][1] = MFMA16(a1, b1, acc[1][1]);
    }
    const float qscale = (which == 0) ? 0.125f : 1.0f;  // fold SCALE into q
#pragma unroll
    for (int i = 0; i < 2; i++)
#pragma unroll
        for (int j = 0; j < 2; j++)
#pragma unroll
            for (int r = 0; r < 4; r++) {
                int il = (wv >> 1) * 32 + i * 16 + quad * 4 + r;
                int cl = (wv & 1) * 32 + j * 16 + col;
                ushort_t hv = f2bf(acc[i][j][r] * qscale);
                if (which == 2) st[cl * 72 + il] = hv;   // transposed: [d][n]
                else            st[il * 72 + cl] = hv;   // [n][d]
            }
    __syncthreads();
    if (which < 2) {
        ushort_t* dst = (which == 0) ? qs : ks;
#pragma unroll
        for (int s = tid; s < 512; s += 256) {
            int rr = s >> 3, dc = (s & 7) * 8;
            *(short8*)&dst[(hidx * 2048 + n0 + rr) * 64 + dc] = *(const short8*)&st[rr * 72 + dc];
        }
    } else {
#pragma unroll
        for (int s = tid; s < 512; s += 256) {
            int d = s >> 3, nc = (s & 7) * 8;
            *(short8*)&vt[(hidx * 64 + d) * 2048 + n0 + nc] = *(const short8*)&st[d * 72 + nc];
        }
    }
}

// ---------------------------------------------------------------- K2a: softmax denominators
// Pure streaming: QK + premix + exp -> partial l_g[i]. No LDS in the loop, no
// barriers. grid (128 qt, 2 b, 4 jslice) x 4 waves -> 4 blocks/CU, 16 waves/CU.
// Each wave owns one 128-j tile; writes one of 4 partial slices (no atomics).
__global__ __launch_bounds__(256, 4) void k_lsum(const ushort_t* __restrict__ qs,
                                                 const ushort_t* __restrict__ ks,
                                                 const float* __restrict__ w_pre,
                                                 float* __restrict__ lpart) {
    __shared__ float wpre_s[64];
    __shared__ float lredL[4][8][16];
    const int tid = threadIdx.x, lane = tid & 63, wv = tid >> 6;
    const int col = lane & 15, quad = lane >> 4;
    const int b = blockIdx.y, n0 = blockIdx.x * 16;
    const int jt = blockIdx.z * 4 + wv;  // this wave's 128-j tile
    if (tid < 64) wpre_s[tid] = w_pre[tid];
    __syncthreads();

    short8 qa0[8], qa1[8];
#pragma unroll
    for (int h = 0; h < 8; h++) {
        const ushort_t* qb = &qs[((b * 8 + h) * 2048 + n0 + col) * 64 + quad * 8];
        qa0[h] = *(const short8*)&qb[0];
        qa1[h] = *(const short8*)&qb[32];
    }
    floatx4 Lacc[8];
#pragma unroll
    for (int g = 0; g < 8; g++) Lacc[g] = (floatx4){0.f, 0.f, 0.f, 0.f};

    for (int jc = 0; jc < 8; jc++) {
        const int j0 = jt * 128 + jc * 16;
        short8 kb0[8], kb1[8];
#pragma unroll
        for (int h = 0; h < 8; h++) {
            const ushort_t* kp = &ks[((b * 8 + h) * 2048 + j0 + col) * 64 + quad * 8];
            kb0[h] = *(const short8*)&kp[0];
            kb1[h] = *(const short8*)&kp[32];
        }
        floatx4 S[8];
#pragma unroll
        for (int h = 0; h < 8; h++) {
            floatx4 a = (floatx4){0.f, 0.f, 0.f, 0.f};
            a = MFMA16(qa0[h], kb0[h], a);
            a = MFMA16(qa1[h], kb1[h], a);
            S[h] = a;
        }
#pragma unroll
        for (int g = 0; g < 8; g++) {
            floatx4 w0 = *(const floatx4*)&wpre_s[g * 8];
            floatx4 w1 = *(const floatx4*)&wpre_s[g * 8 + 4];
            floatx4 s4 = (floatx4){0.f, 0.f, 0.f, 0.f};
#pragma unroll
            for (int h = 0; h < 4; h++) s4 = fma4(w0[h], S[h], s4);
#pragma unroll
            for (int h = 0; h < 4; h++) s4 = fma4(w1[h], S[h + 4], s4);
            floatx4 u4;
            u4[0] = __expf(s4[0]);
            u4[1] = __expf(s4[1]);
            u4[2] = __expf(s4[2]);
            u4[3] = __expf(s4[3]);
            Lacc[g] += u4;
        }
    }
    // reduce over the 16 j-columns (lane&15), then across the block's 4 waves
#pragma unroll
    for (int g = 0; g < 8; g++)
#pragma unroll
        for (int r = 0; r < 4; r++) {
            float v = Lacc[g][r];
            v += __shfl_xor(v, 1, 64);
            v += __shfl_xor(v, 2, 64);
            v += __shfl_xor(v, 4, 64);
            v += __shfl_xor(v, 8, 64);
            if (col == 0) lredL[wv][g][quad * 4 + r] = v;
        }
    __syncthreads();
    if (tid < 128) {
        int g = tid >> 4, ii = tid & 15;
        float s = lredL[0][g][ii] + lredL[1][g][ii] + lredL[2][g][ii] + lredL[3][g][ii];
        lpart[(blockIdx.z * 16 + b * 8 + g) * 2048 + n0 + ii] = s;
    }
}

// ---------------------------------------------------------------- K2b: normalized+mixed attn, PV
// j-split 2 -> grid 512, LDS 54 KB -> 2 blocks/CU (4 waves/SIMD). Single-buffered
// A with two lgkm-only barriers per tile; K/V register-prefetched (vmcnt stays in
// flight across barriers). Writes fp32 partial O-hat to workspace.
__global__ __launch_bounds__(512, 4) void k_attn(const ushort_t* __restrict__ qs,
                                                 const ushort_t* __restrict__ ks,
                                                 const ushort_t* __restrict__ vt,
                                                 const float* __restrict__ w_pre,
                                                 const float* __restrict__ w_post,
                                                 const float* __restrict__ lpart,
                                                 float* __restrict__ opart) {
    __shared__ __align__(16) ushort_t qlds[8 * 16 * 72];  // q tiles, 8 heads x 16 rows
    __shared__ __align__(16) ushort_t A[8 * 16 * 136];    // mixed attn (single buffer)
    __shared__ __align__(16) float wbuf[128];             // fp32 w_pre | w_post
    __shared__ __align__(16) float linv_s[8][16];         // 1 / l_g[i]
    const int tid = threadIdx.x, lane = tid & 63, wv = tid >> 6;
    const int col = lane & 15, quad = lane >> 4;
    const int b = blockIdx.y, n0 = blockIdx.x * 16;
    const int jb = blockIdx.z * 8;  // this block's jt range [jb, jb+8)
    const int e = wv;               // wave's output head

    if (tid < 64) wbuf[tid] = w_pre[tid];
    else if (tid < 128) wbuf[tid] = w_post[tid - 64];
    if (tid < 128) {  // 1/l from the 4 partial slices
        int g = tid >> 4, ii = tid & 15;
        float l = 0.f;
#pragma unroll
        for (int p = 0; p < 4; p++) l += lpart[(p * 16 + b * 8 + g) * 2048 + n0 + ii];
        linv_s[g][ii] = 1.0f / l;
    }
    for (int c = tid; c < 1024; c += 512) {
        int hh = c >> 7, rem = c & 127, ii = rem >> 3, dc = (rem & 7) * 8;
        *(short8*)&qlds[(hh * 16 + ii) * 72 + dc] =
            *(const short8*)&qs[((b * 8 + hh) * 2048 + n0 + ii) * 64 + dc];
    }

    // prefetch K and V for the first tile of our range
    short8 kb0[8], kb1[8];
#pragma unroll
    for (int h = 0; h < 8; h++) {
        const ushort_t* kp = &ks[((b * 8 + h) * 2048 + jb * 128 + wv * 16 + col) * 64 + quad * 8];
        kb0[h] = *(const short8*)&kp[0];
        kb1[h] = *(const short8*)&kp[32];
    }
    short8 vbr[16];
#pragma unroll
    for (int k2 = 0; k2 < 4; k2++)
#pragma unroll
        for (int nt = 0; nt < 4; nt++)
            vbr[k2 * 4 + nt] = *(const short8*)&vt[((b * 8 + e) * 64 + nt * 16 + col) * 2048 +
                                                   jb * 128 + k2 * 32 + quad * 8];
    floatx4 Oa[4];
#pragma unroll
    for (int nt = 0; nt < 4; nt++) Oa[nt] = (floatx4){0.f, 0.f, 0.f, 0.f};
    __syncthreads();  // qlds + wbuf + linv visible

    for (int t = 0; t < 8; t++) {
        const int jt = jb + t;
        // ---- QK (q re-read from LDS; K regs prefetched)
        floatx4 S[8];
#pragma unroll
        for (int h = 0; h < 8; h++) {
            const ushort_t* qb = &qlds[(h * 16 + col) * 72 + quad * 8];
            short8 a0 = *(const short8*)&qb[0];
            short8 a1 = *(const short8*)&qb[32];
            floatx4 a = (floatx4){0.f, 0.f, 0.f, 0.f};
            a = MFMA16(a0, kb0[h], a);
            a = MFMA16(a1, kb1[h], a);
            S[h] = a;
        }
        if (t < 7) {  // prefetch K for next tile
            const int jw = (jt + 1) * 128 + wv * 16;
#pragma unroll
            for (int h = 0; h < 8; h++) {
                const ushort_t* kp = &ks[((b * 8 + h) * 2048 + jw + col) * 64 + quad * 8];
                kb0[h] = *(const short8*)&kp[0];
                kb1[h] = *(const short8*)&kp[32];
            }
        }
        // ---- premix + exp + normalize -> Ug (live across barrier)
        floatx4 Ug[8];
#pragma unroll
        for (int g = 0; g < 8; g++) {
            floatx4 w0 = *(const floatx4*)&wbuf[g * 8];
            floatx4 w1 = *(const floatx4*)&wbuf[g * 8 + 4];
            floatx4 s4 = (floatx4){0.f, 0.f, 0.f, 0.f};
#pragma unroll
            for (int h = 0; h < 4; h++) s4 = fma4(w0[h], S[h], s4);
#pragma unroll
            for (int h = 0; h < 4; h++) s4 = fma4(w1[h], S[h + 4], s4);
            floatx4 lg = *(const floatx4*)&linv_s[g][quad * 4];
            floatx4 u4;
            u4[0] = __expf(s4[0]) * lg[0];
            u4[1] = __expf(s4[1]) * lg[1];
            u4[2] = __expf(s4[2]) * lg[2];
            u4[3] = __expf(s4[3]) * lg[3];
            Ug[g] = u4;
        }
        // ---- barrier 1: all waves' PV reads of A (prev tile) complete
        asm volatile("s_waitcnt lgkmcnt(0)\n\ts_barrier" ::: "memory");
        // ---- post-mix: A_e = sum_g w_post[e,g] * Ug -> LDS (A-operand layout)
#pragma unroll
        for (int e2 = 0; e2 < 8; e2++) {
            floatx4 wqa = *(const floatx4*)&wbuf[64 + e2 * 8];
            floatx4 wqb = *(const floatx4*)&wbuf[64 + e2 * 8 + 4];
            floatx4 a4 = (floatx4){0.f, 0.f, 0.f, 0.f};
#pragma unroll
            for (int g = 0; g < 4; g++) a4 = fma4(wqa[g], Ug[g], a4);
#pragma unroll
            for (int g = 0; g < 4; g++) a4 = fma4(wqb[g], Ug[g + 4], a4);
#pragma unroll
            for (int r = 0; r < 4; r++)
                A[(e2 * 16 + quad * 4 + r) * 136 + wv * 16 + col] = f2bf(a4[r]);
        }
        // ---- barrier 2: A writes visible; global prefetches stay in flight
        asm volatile("s_waitcnt lgkmcnt(0)\n\ts_barrier" ::: "memory");
        // ---- PV: O_e += A_e @ V_e over this 128-j tile
#pragma unroll
        for (int k2 = 0; k2 < 4; k2++) {
            short8 af = *(const short8*)&A[(e * 16 + col) * 136 + k2 * 32 + quad * 8];
#pragma unroll
            for (int nt = 0; nt < 4; nt++) Oa[nt] = MFMA16(af, vbr[k2 * 4 + nt], Oa[nt]);
        }
        if (t < 7) {  // prefetch V for next tile
            const int j0 = (jt + 1) * 128;
#pragma unroll
            for (int k2 = 0; k2 < 4; k2++)
#pragma unroll
                for (int nt = 0; nt < 4; nt++)
                    vbr[k2 * 4 + nt] =
                        *(const short8*)&vt[((b * 8 + e) * 64 + nt * 16 + col) * 2048 + j0 +
                                            k2 * 32 + quad * 8];
        }
    }

    // ---- epilogue: fp32 partial O-hat for this j-half
#pragma unroll
    for (int nt = 0; nt < 4; nt++)
#pragma unroll
        for (int r = 0; r < 4; r++)
            opart[((blockIdx.z * 2 + b) * 2048 + n0 + quad * 4 + r) * 512 + e * 64 + nt * 16 +
                  col] = Oa[nt][r];
}

// ---------------------------------------------------------------- K3: combine halves + out proj
// out[16 x 512] = (Ohat_0 + Ohat_1) @ w_out + bias.  grid (128 qt, 2 b, 2 cs).
__global__ __launch_bounds__(256) void k_proj(const float* __restrict__ opart,
                                              const ushort_t* __restrict__ wot,
                                              const float* __restrict__ bias,
                                              float* __restrict__ out) {
    __shared__ __align__(16) ushort_t oline[16 * 520];
    const int tid = threadIdx.x, lane = tid & 63, wv = tid >> 6;
    const int col = lane & 15, quad = lane >> 4;
    const int b = blockIdx.y, n0 = blockIdx.x * 16;
    // stage summed O-hat (bf16) to LDS: 16 rows x 512 cols
#pragma unroll
    for (int it = 0; it < 8; it++) {
        int idx = it * 256 + tid;
        int row = idx >> 7, c4 = (idx & 127) << 2;
        floatx4 v0 = *(const floatx4*)&opart[((0 + b) * 2048 + n0 + row) * 512 + c4];
        floatx4 v1 = *(const floatx4*)&opart[((2 + b) * 2048 + n0 + row) * 512 + c4];
        floatx4 s = v0 + v1;
        short4v o;
        o[0] = (short)f2bf(s[0]);
        o[1] = (short)f2bf(s[1]);
        o[2] = (short)f2bf(s[2]);
        o[3] = (short)f2bf(s[3]);
        *(short4v*)&oline[row * 520 + c4] = o;
    }
    __syncthreads();
#pragma unroll
    for (int ct = 0; ct < 4; ct++) {
        floatx4 acc = (floatx4){0.f, 0.f, 0.f, 0.f};
        const int c = blockIdx.z * 256 + wv * 64 + ct * 16 + col;
#pragma unroll
        for (int k2 = 0; k2 < 16; k2++) {
            short8 af = *(const short8*)&oline[col * 520 + k2 * 32 + quad * 8];
            short8 bf = *(const short8*)&wot[c * 512 + k2 * 32 + quad * 8];
            acc = MFMA16(af, bf, acc);
        }
        float bz = bias[c];
#pragma unroll
        for (int r = 0; r < 4; r++)
            out[(b * 2048 + n0 + quad * 4 + r) * 512 + c] = acc[r] + bz;
    }
}

// ---------------------------------------------------------------- launch
extern "C" void kernel_launch(void* const* d_in, const int* in_sizes, int n_in,
                              void* d_out, int out_size, void* d_ws, size_t ws_size,
                              hipStream_t stream) {
    const float* x = (const float*)d_in[0];
    const float* w_qkv = (const float*)d_in[1];
    const float* w_pre = (const float*)d_in[2];
    const float* w_post = (const float*)d_in[3];
    const float* w_out = (const float*)d_in[4];
    const float* b_out = (const float*)d_in[5];
    char* ws = (char*)d_ws;
    ushort_t* qs = (ushort_t*)(ws);                            // 4 MB   [b,h,n,d] (pre-scaled)
    ushort_t* ks = (ushort_t*)(ws + (4u << 20));               // 4 MB   [b,h,n,d]
    ushort_t* vt = (ushort_t*)(ws + (8u << 20));               // 4 MB   [b,h,d,n]
    ushort_t* xb = (ushort_t*)(ws + (12u << 20));              // 4 MB   x in bf16
    ushort_t* wt = (ushort_t*)(ws + (16u << 20));              // 1.5 MB w_qkv^T bf16
    ushort_t* wot = (ushort_t*)(ws + (16u << 20) + 1572864u);  // 0.5 MB w_out^T bf16
    float* lpart = (float*)(ws + (18u << 20));                 // 0.5 MB 4 partial l slices
    float* opart = (float*)(ws + (19u << 20));                 // 16 MB  2 partial O-hat (fp32)
    float* out = (float*)d_out;

    k_cvt<<<dim3(2048), dim3(256), 0, stream>>>((const floatx4*)x, (short4v*)xb, 524288);
    k_transpose_cvt<<<dim3(48, 16), dim3(256), 0, stream>>>(w_qkv, wt, 512, 1536);
    k_transpose_cvt<<<dim3(16, 16), dim3(256), 0, stream>>>(w_out, wot, 512, 512);
    k_qkv<<<dim3(24, 64), dim3(256), 0, stream>>>(xb, wt, qs, ks, vt);
    k_lsum<<<dim3(128, 2, 4), dim3(256), 0, stream>>>(qs, ks, w_pre, lpart);
    k_attn<<<dim3(128, 2, 2), dim3(512), 0, stream>>>(qs, ks, vt, w_pre, w_post, lpart, opart);
    k_proj<<<dim3(128, 2, 2), dim3(256), 0, stream>>>(opart, wot, b_out, out);
}

// Round 4
// 410.451 us; speedup vs baseline: 1.4451x; 1.4451x over previous
//
#include <hip/hip_runtime.h>
#include <hip/hip_bf16.h>

typedef unsigned short ushort_t;
typedef __attribute__((ext_vector_type(8))) short short8;
typedef __attribute__((ext_vector_type(4))) short short4v;
typedef __attribute__((ext_vector_type(4))) float floatx4;

#define MFMA16(a, b, c) __builtin_amdgcn_mfma_f32_16x16x32_bf16(a, b, c, 0, 0, 0)

__device__ __forceinline__ float bf2f(ushort_t u) {
    unsigned int v = ((unsigned int)u) << 16;
    return __int_as_float((int)v);
}
__device__ __forceinline__ ushort_t f2bf(float f) {
    unsigned int x = (unsigned int)__float_as_int(f);
    unsigned int r = (x + 0x7FFFu + ((x >> 16) & 1u)) >> 16;
    return (ushort_t)r;
}
__device__ __forceinline__ floatx4 fma4(float a, floatx4 b, floatx4 c) {
    c[0] = fmaf(a, b[0], c[0]);
    c[1] = fmaf(a, b[1], c[1]);
    c[2] = fmaf(a, b[2], c[2]);
    c[3] = fmaf(a, b[3], c[3]);
    return c;
}

// ---------------------------------------------------------------- fp32 -> bf16 convert
__global__ __launch_bounds__(256) void k_cvt(const floatx4* __restrict__ src,
                                             short4v* __restrict__ dst, int n4) {
    int i = blockIdx.x * 256 + threadIdx.x;
    if (i < n4) {
        floatx4 v = src[i];
        short4v o;
        o[0] = (short)f2bf(v[0]);
        o[1] = (short)f2bf(v[1]);
        o[2] = (short)f2bf(v[2]);
        o[3] = (short)f2bf(v[3]);
        dst[i] = o;
    }
}

// ---------------------------------------------------------------- fp32 transpose -> bf16
__global__ __launch_bounds__(256) void k_transpose_cvt(const float* __restrict__ src,
                                                       ushort_t* __restrict__ dst, int R, int C) {
    __shared__ float t[32][33];
    int tx = threadIdx.x & 31, ty = threadIdx.x >> 5;
    int r0 = blockIdx.y * 32, c0 = blockIdx.x * 32;
    for (int y = ty; y < 32; y += 8) t[y][tx] = src[(r0 + y) * C + c0 + tx];
    __syncthreads();
    for (int y = ty; y < 32; y += 8) dst[(c0 + y) * R + r0 + tx] = f2bf(t[tx][y]);
}

// ---------------------------------------------------------------- K1: qkv = x @ w_qkv, scatter q/k/vT
__global__ __launch_bounds__(256) void k_qkv(const ushort_t* __restrict__ x,
                                             const ushort_t* __restrict__ wt,
                                             ushort_t* __restrict__ qs,
                                             ushort_t* __restrict__ ks,
                                             ushort_t* __restrict__ vt) {
    __shared__ __align__(16) ushort_t st[64 * 72];
    const int tid = threadIdx.x, lane = tid & 63, wv = tid >> 6;
    const int col = lane & 15, quad = lane >> 4;
    const int row0 = blockIdx.y * 64 + (wv >> 1) * 32;
    const int c0 = blockIdx.x * 64 + (wv & 1) * 32;
    const int which = blockIdx.x >> 3, hh = blockIdx.x & 7;
    const int brow0 = blockIdx.y * 64;
    const int bb = brow0 >> 11, n0 = brow0 & 2047;
    const int hidx = bb * 8 + hh;
    floatx4 acc[2][2];
#pragma unroll
    for (int i = 0; i < 2; i++)
#pragma unroll
        for (int j = 0; j < 2; j++) acc[i][j] = (floatx4){0.f, 0.f, 0.f, 0.f};
    for (int k0 = 0; k0 < 512; k0 += 32) {
        const int ko = k0 + quad * 8;
        short8 a0 = *(const short8*)&x[(row0 + col) * 512 + ko];
        short8 a1 = *(const short8*)&x[(row0 + 16 + col) * 512 + ko];
        short8 b0 = *(const short8*)&wt[(c0 + col) * 512 + ko];
        short8 b1 = *(const short8*)&wt[(c0 + 16 + col) * 512 + ko];
        acc[0][0] = MFMA16(a0, b0, acc[0][0]);
        acc[0][1] = MFMA16(a0, b1, acc[0][1]);
        acc[1][0] = MFMA16(a1, b0, acc[1][0]);
        acc[1][1] = MFMA16(a1, b1, acc[1][1]);
    }
    const float qscale = (which == 0) ? 0.125f : 1.0f;  // fold SCALE into q
#pragma unroll
    for (int i = 0; i < 2; i++)
#pragma unroll
        for (int j = 0; j < 2; j++)
#pragma unroll
            for (int r = 0; r < 4; r++) {
                int il = (wv >> 1) * 32 + i * 16 + quad * 4 + r;
                int cl = (wv & 1) * 32 + j * 16 + col;
                ushort_t hv = f2bf(acc[i][j][r] * qscale);
                if (which == 2) st[cl * 72 + il] = hv;   // transposed: [d][n]
                else            st[il * 72 + cl] = hv;   // [n][d]
            }
    __syncthreads();
    if (which < 2) {
        ushort_t* dst = (which == 0) ? qs : ks;
#pragma unroll
        for (int s = tid; s < 512; s += 256) {
            int rr = s >> 3, dc = (s & 7) * 8;
            *(short8*)&dst[(hidx * 2048 + n0 + rr) * 64 + dc] = *(const short8*)&st[rr * 72 + dc];
        }
    } else {
#pragma unroll
        for (int s = tid; s < 512; s += 256) {
            int d = s >> 3, nc = (s & 7) * 8;
            *(short8*)&vt[(hidx * 64 + d) * 2048 + n0 + nc] = *(const short8*)&st[d * 72 + nc];
        }
    }
}

// ---------------------------------------------------------------- K2a: softmax denominators
// Streaming QK + premix + exp -> partial l_g[i]. Low-register: Q staged in LDS
// (re-read per iter), K loaded inline (TLP hides latency at 4 blocks/CU).
__global__ __launch_bounds__(256, 4) void k_lsum(const ushort_t* __restrict__ qs,
                                                 const ushort_t* __restrict__ ks,
                                                 const float* __restrict__ w_pre,
                                                 float* __restrict__ lpart) {
    __shared__ float wpre_s[64];
    __shared__ __align__(16) ushort_t qlds[8 * 16 * 72];
    __shared__ float lredL[4][8][16];
    const int tid = threadIdx.x, lane = tid & 63, wv = tid >> 6;
    const int col = lane & 15, quad = lane >> 4;
    const int b = blockIdx.y, n0 = blockIdx.x * 16;
    const int jt = blockIdx.z * 4 + wv;  // this wave's 512-j slice -> 8 x 16-j chunks
    if (tid < 64) wpre_s[tid] = w_pre[tid];
    for (int c = tid; c < 1024; c += 256) {
        int hh = c >> 7, rem = c & 127, ii = rem >> 3, dc = (rem & 7) * 8;
        *(short8*)&qlds[(hh * 16 + ii) * 72 + dc] =
            *(const short8*)&qs[((b * 8 + hh) * 2048 + n0 + ii) * 64 + dc];
    }
    __syncthreads();

    floatx4 Lacc[8];
#pragma unroll
    for (int g = 0; g < 8; g++) Lacc[g] = (floatx4){0.f, 0.f, 0.f, 0.f};

    for (int jc = 0; jc < 8; jc++) {
        const int j0 = jt * 128 + jc * 16;
        floatx4 S[8];
#pragma unroll
        for (int h = 0; h < 8; h++) {
            const ushort_t* qb = &qlds[(h * 16 + col) * 72 + quad * 8];
            short8 a0 = *(const short8*)&qb[0];
            short8 a1 = *(const short8*)&qb[32];
            const ushort_t* kp = &ks[((b * 8 + h) * 2048 + j0 + col) * 64 + quad * 8];
            short8 b0 = *(const short8*)&kp[0];
            short8 b1 = *(const short8*)&kp[32];
            floatx4 a = (floatx4){0.f, 0.f, 0.f, 0.f};
            a = MFMA16(a0, b0, a);
            a = MFMA16(a1, b1, a);
            S[h] = a;
        }
#pragma unroll
        for (int g = 0; g < 8; g++) {
            floatx4 w0 = *(const floatx4*)&wpre_s[g * 8];
            floatx4 w1 = *(const floatx4*)&wpre_s[g * 8 + 4];
            floatx4 s4 = (floatx4){0.f, 0.f, 0.f, 0.f};
#pragma unroll
            for (int h = 0; h < 4; h++) s4 = fma4(w0[h], S[h], s4);
#pragma unroll
            for (int h = 0; h < 4; h++) s4 = fma4(w1[h], S[h + 4], s4);
            floatx4 u4;
            u4[0] = __expf(s4[0]);
            u4[1] = __expf(s4[1]);
            u4[2] = __expf(s4[2]);
            u4[3] = __expf(s4[3]);
            Lacc[g] += u4;
        }
    }
    // reduce over the 16 j-columns (lane&15), then across the block's 4 waves
#pragma unroll
    for (int g = 0; g < 8; g++)
#pragma unroll
        for (int r = 0; r < 4; r++) {
            float v = Lacc[g][r];
            v += __shfl_xor(v, 1, 64);
            v += __shfl_xor(v, 2, 64);
            v += __shfl_xor(v, 4, 64);
            v += __shfl_xor(v, 8, 64);
            if (col == 0) lredL[wv][g][quad * 4 + r] = v;
        }
    __syncthreads();
    if (tid < 128) {
        int g = tid >> 4, ii = tid & 15;
        float s = lredL[0][g][ii] + lredL[1][g][ii] + lredL[2][g][ii] + lredL[3][g][ii];
        lpart[(blockIdx.z * 16 + b * 8 + g) * 2048 + n0 + ii] = s;
    }
}

// ---------------------------------------------------------------- K2b: normalized+mixed attn, PV
// j-split 2 -> grid 512. Low-register (~115): NO prefetch arrays; K/V loaded
// inline; TLP (2 blocks/CU, 4 waves/SIMD) hides latency. Single-buffered A with
// two lgkm-only barriers per tile. Writes fp32 partial O-hat.
__global__ __launch_bounds__(512, 4) void k_attn(const ushort_t* __restrict__ qs,
                                                 const ushort_t* __restrict__ ks,
                                                 const ushort_t* __restrict__ vt,
                                                 const float* __restrict__ w_pre,
                                                 const float* __restrict__ w_post,
                                                 const float* __restrict__ lpart,
                                                 float* __restrict__ opart) {
    __shared__ __align__(16) ushort_t qlds[8 * 16 * 72];  // q tiles, 8 heads x 16 rows
    __shared__ __align__(16) ushort_t A[8 * 16 * 136];    // mixed attn (single buffer)
    __shared__ __align__(16) float wbuf[128];             // fp32 w_pre | w_post
    __shared__ __align__(16) float linv_s[8][16];         // 1 / l_g[i]
    const int tid = threadIdx.x, lane = tid & 63, wv = tid >> 6;
    const int col = lane & 15, quad = lane >> 4;
    const int b = blockIdx.y, n0 = blockIdx.x * 16;
    const int jb = blockIdx.z * 8;  // this block's jt range [jb, jb+8)
    const int e = wv;               // wave's output head

    if (tid < 64) wbuf[tid] = w_pre[tid];
    else if (tid < 128) wbuf[tid] = w_post[tid - 64];
    if (tid < 128) {  // 1/l from the 4 partial slices
        int g = tid >> 4, ii = tid & 15;
        float l = 0.f;
#pragma unroll
        for (int p = 0; p < 4; p++) l += lpart[(p * 16 + b * 8 + g) * 2048 + n0 + ii];
        linv_s[g][ii] = 1.0f / l;
    }
    for (int c = tid; c < 1024; c += 512) {
        int hh = c >> 7, rem = c & 127, ii = rem >> 3, dc = (rem & 7) * 8;
        *(short8*)&qlds[(hh * 16 + ii) * 72 + dc] =
            *(const short8*)&qs[((b * 8 + hh) * 2048 + n0 + ii) * 64 + dc];
    }
    floatx4 Oa[4];
#pragma unroll
    for (int nt = 0; nt < 4; nt++) Oa[nt] = (floatx4){0.f, 0.f, 0.f, 0.f};
    __syncthreads();  // qlds + wbuf + linv visible

    for (int t = 0; t < 8; t++) {
        const int jt = jb + t;
        // ---- QK for 8 heads; K loaded inline (no persistent arrays)
        floatx4 S[8];
#pragma unroll
        for (int h = 0; h < 8; h++) {
            const ushort_t* qb = &qlds[(h * 16 + col) * 72 + quad * 8];
            short8 a0 = *(const short8*)&qb[0];
            short8 a1 = *(const short8*)&qb[32];
            const ushort_t* kp = &ks[((b * 8 + h) * 2048 + jt * 128 + wv * 16 + col) * 64 +
                                     quad * 8];
            short8 b0 = *(const short8*)&kp[0];
            short8 b1 = *(const short8*)&kp[32];
            floatx4 a = (floatx4){0.f, 0.f, 0.f, 0.f};
            a = MFMA16(a0, b0, a);
            a = MFMA16(a1, b1, a);
            S[h] = a;
        }
        // ---- premix + exp + normalize -> Ug
        floatx4 Ug[8];
#pragma unroll
        for (int g = 0; g < 8; g++) {
            floatx4 w0 = *(const floatx4*)&wbuf[g * 8];
            floatx4 w1 = *(const floatx4*)&wbuf[g * 8 + 4];
            floatx4 s4 = (floatx4){0.f, 0.f, 0.f, 0.f};
#pragma unroll
            for (int h = 0; h < 4; h++) s4 = fma4(w0[h], S[h], s4);
#pragma unroll
            for (int h = 0; h < 4; h++) s4 = fma4(w1[h], S[h + 4], s4);
            floatx4 lg = *(const floatx4*)&linv_s[g][quad * 4];
            floatx4 u4;
            u4[0] = __expf(s4[0]) * lg[0];
            u4[1] = __expf(s4[1]) * lg[1];
            u4[2] = __expf(s4[2]) * lg[2];
            u4[3] = __expf(s4[3]) * lg[3];
            Ug[g] = u4;
        }
        // ---- barrier 1: all waves' PV reads of A (prev tile) complete
        asm volatile("s_waitcnt lgkmcnt(0)\n\ts_barrier" ::: "memory");
        // ---- post-mix: A_e = sum_g w_post[e,g] * Ug -> LDS (A-operand layout)
#pragma unroll
        for (int e2 = 0; e2 < 8; e2++) {
            floatx4 wqa = *(const floatx4*)&wbuf[64 + e2 * 8];
            floatx4 wqb = *(const floatx4*)&wbuf[64 + e2 * 8 + 4];
            floatx4 a4 = (floatx4){0.f, 0.f, 0.f, 0.f};
#pragma unroll
            for (int g = 0; g < 4; g++) a4 = fma4(wqa[g], Ug[g], a4);
#pragma unroll
            for (int g = 0; g < 4; g++) a4 = fma4(wqb[g], Ug[g + 4], a4);
#pragma unroll
            for (int r = 0; r < 4; r++)
                A[(e2 * 16 + quad * 4 + r) * 136 + wv * 16 + col] = f2bf(a4[r]);
        }
        // ---- barrier 2: A writes visible
        asm volatile("s_waitcnt lgkmcnt(0)\n\ts_barrier" ::: "memory");
        // ---- PV: O_e += A_e @ V_e; V loaded inline
#pragma unroll
        for (int k2 = 0; k2 < 4; k2++) {
            short8 af = *(const short8*)&A[(e * 16 + col) * 136 + k2 * 32 + quad * 8];
#pragma unroll
            for (int nt = 0; nt < 4; nt++) {
                short8 bv = *(const short8*)&vt[((b * 8 + e) * 64 + nt * 16 + col) * 2048 +
                                                jt * 128 + k2 * 32 + quad * 8];
                Oa[nt] = MFMA16(af, bv, Oa[nt]);
            }
        }
    }

    // ---- epilogue: fp32 partial O-hat for this j-half
#pragma unroll
    for (int nt = 0; nt < 4; nt++)
#pragma unroll
        for (int r = 0; r < 4; r++)
            opart[((blockIdx.z * 2 + b) * 2048 + n0 + quad * 4 + r) * 512 + e * 64 + nt * 16 +
                  col] = Oa[nt][r];
}

// ---------------------------------------------------------------- K3: combine halves + out proj
__global__ __launch_bounds__(256) void k_proj(const float* __restrict__ opart,
                                              const ushort_t* __restrict__ wot,
                                              const float* __restrict__ bias,
                                              float* __restrict__ out) {
    __shared__ __align__(16) ushort_t oline[16 * 520];
    const int tid = threadIdx.x, lane = tid & 63, wv = tid >> 6;
    const int col = lane & 15, quad = lane >> 4;
    const int b = blockIdx.y, n0 = blockIdx.x * 16;
#pragma unroll
    for (int it = 0; it < 8; it++) {
        int idx = it * 256 + tid;
        int row = idx >> 7, c4 = (idx & 127) << 2;
        floatx4 v0 = *(const floatx4*)&opart[((0 + b) * 2048 + n0 + row) * 512 + c4];
        floatx4 v1 = *(const floatx4*)&opart[((2 + b) * 2048 + n0 + row) * 512 + c4];
        floatx4 s = v0 + v1;
        short4v o;
        o[0] = (short)f2bf(s[0]);
        o[1] = (short)f2bf(s[1]);
        o[2] = (short)f2bf(s[2]);
        o[3] = (short)f2bf(s[3]);
        *(short4v*)&oline[row * 520 + c4] = o;
    }
    __syncthreads();
#pragma unroll
    for (int ct = 0; ct < 4; ct++) {
        floatx4 acc = (floatx4){0.f, 0.f, 0.f, 0.f};
        const int c = blockIdx.z * 256 + wv * 64 + ct * 16 + col;
#pragma unroll
        for (int k2 = 0; k2 < 16; k2++) {
            short8 af = *(const short8*)&oline[col * 520 + k2 * 32 + quad * 8];
            short8 bf = *(const short8*)&wot[c * 512 + k2 * 32 + quad * 8];
            acc = MFMA16(af, bf, acc);
        }
        float bz = bias[c];
#pragma unroll
        for (int r = 0; r < 4; r++)
            out[(b * 2048 + n0 + quad * 4 + r) * 512 + c] = acc[r] + bz;
    }
}

// ---------------------------------------------------------------- launch
extern "C" void kernel_launch(void* const* d_in, const int* in_sizes, int n_in,
                              void* d_out, int out_size, void* d_ws, size_t ws_size,
                              hipStream_t stream) {
    const float* x = (const float*)d_in[0];
    const float* w_qkv = (const float*)d_in[1];
    const float* w_pre = (const float*)d_in[2];
    const float* w_post = (const float*)d_in[3];
    const float* w_out = (const float*)d_in[4];
    const float* b_out = (const float*)d_in[5];
    char* ws = (char*)d_ws;
    ushort_t* qs = (ushort_t*)(ws);                            // 4 MB   [b,h,n,d] (pre-scaled)
    ushort_t* ks = (ushort_t*)(ws + (4u << 20));               // 4 MB   [b,h,n,d]
    ushort_t* vt = (ushort_t*)(ws + (8u << 20));               // 4 MB   [b,h,d,n]
    ushort_t* xb = (ushort_t*)(ws + (12u << 20));              // 4 MB   x in bf16
    ushort_t* wt = (ushort_t*)(ws + (16u << 20));              // 1.5 MB w_qkv^T bf16
    ushort_t* wot = (ushort_t*)(ws + (16u << 20) + 1572864u);  // 0.5 MB w_out^T bf16
    float* lpart = (float*)(ws + (18u << 20));                 // 0.5 MB 4 partial l slices
    float* opart = (float*)(ws + (19u << 20));                 // 16 MB  2 partial O-hat (fp32)
    float* out = (float*)d_out;

    k_cvt<<<dim3(2048), dim3(256), 0, stream>>>((const floatx4*)x, (short4v*)xb, 524288);
    k_transpose_cvt<<<dim3(48, 16), dim3(256), 0, stream>>>(w_qkv, wt, 512, 1536);
    k_transpose_cvt<<<dim3(16, 16), dim3(256), 0, stream>>>(w_out, wot, 512, 512);
    k_qkv<<<dim3(24, 64), dim3(256), 0, stream>>>(xb, wt, qs, ks, vt);
    k_lsum<<<dim3(128, 2, 4), dim3(256), 0, stream>>>(qs, ks, w_pre, lpart);
    k_attn<<<dim3(128, 2, 2), dim3(512), 0, stream>>>(qs, ks, vt, w_pre, w_post, lpart, opart);
    k_proj<<<dim3(128, 2, 2), dim3(256), 0, stream>>>(opart, wot, b_out, out);
}

// Round 5
// 333.957 us; speedup vs baseline: 1.7761x; 1.2291x over previous
//
#include <hip/hip_runtime.h>
#include <hip/hip_bf16.h>

typedef unsigned short ushort_t;
typedef __attribute__((ext_vector_type(8))) short short8;
typedef __attribute__((ext_vector_type(4))) short short4v;
typedef __attribute__((ext_vector_type(4))) float floatx4;

#define MFMA16(a, b, c) __builtin_amdgcn_mfma_f32_16x16x32_bf16(a, b, c, 0, 0, 0)

__device__ __forceinline__ float bf2f(ushort_t u) {
    unsigned int v = ((unsigned int)u) << 16;
    return __int_as_float((int)v);
}
__device__ __forceinline__ ushort_t f2bf(float f) {
    unsigned int x = (unsigned int)__float_as_int(f);
    unsigned int r = (x + 0x7FFFu + ((x >> 16) & 1u)) >> 16;
    return (ushort_t)r;
}
__device__ __forceinline__ floatx4 fma4(float a, floatx4 b, floatx4 c) {
    c[0] = fmaf(a, b[0], c[0]);
    c[1] = fmaf(a, b[1], c[1]);
    c[2] = fmaf(a, b[2], c[2]);
    c[3] = fmaf(a, b[3], c[3]);
    return c;
}

// ---------------------------------------------------------------- fp32 -> bf16 convert
__global__ __launch_bounds__(256) void k_cvt(const floatx4* __restrict__ src,
                                             short4v* __restrict__ dst, int n4) {
    int i = blockIdx.x * 256 + threadIdx.x;
    if (i < n4) {
        floatx4 v = src[i];
        short4v o;
        o[0] = (short)f2bf(v[0]);
        o[1] = (short)f2bf(v[1]);
        o[2] = (short)f2bf(v[2]);
        o[3] = (short)f2bf(v[3]);
        dst[i] = o;
    }
}

// ---------------------------------------------------------------- fp32 transpose -> bf16
__global__ __launch_bounds__(256) void k_transpose_cvt(const float* __restrict__ src,
                                                       ushort_t* __restrict__ dst, int R, int C) {
    __shared__ float t[32][33];
    int tx = threadIdx.x & 31, ty = threadIdx.x >> 5;
    int r0 = blockIdx.y * 32, c0 = blockIdx.x * 32;
    for (int y = ty; y < 32; y += 8) t[y][tx] = src[(r0 + y) * C + c0 + tx];
    __syncthreads();
    for (int y = ty; y < 32; y += 8) dst[(c0 + y) * R + r0 + tx] = f2bf(t[tx][y]);
}

// ---------------------------------------------------------------- K1: qkv = x @ w_qkv, scatter q/k/vT
__global__ __launch_bounds__(256) void k_qkv(const ushort_t* __restrict__ x,
                                             const ushort_t* __restrict__ wt,
                                             ushort_t* __restrict__ qs,
                                             ushort_t* __restrict__ ks,
                                             ushort_t* __restrict__ vt) {
    __shared__ __align__(16) ushort_t st[64 * 72];
    const int tid = threadIdx.x, lane = tid & 63, wv = tid >> 6;
    const int col = lane & 15, quad = lane >> 4;
    const int row0 = blockIdx.y * 64 + (wv >> 1) * 32;
    const int c0 = blockIdx.x * 64 + (wv & 1) * 32;
    const int which = blockIdx.x >> 3, hh = blockIdx.x & 7;
    const int brow0 = blockIdx.y * 64;
    const int bb = brow0 >> 11, n0 = brow0 & 2047;
    const int hidx = bb * 8 + hh;
    floatx4 acc[2][2];
#pragma unroll
    for (int i = 0; i < 2; i++)
#pragma unroll
        for (int j = 0; j < 2; j++) acc[i][j] = (floatx4){0.f, 0.f, 0.f, 0.f};
    for (int k0 = 0; k0 < 512; k0 += 32) {
        const int ko = k0 + quad * 8;
        short8 a0 = *(const short8*)&x[(row0 + col) * 512 + ko];
        short8 a1 = *(const short8*)&x[(row0 + 16 + col) * 512 + ko];
        short8 b0 = *(const short8*)&wt[(c0 + col) * 512 + ko];
        short8 b1 = *(const short8*)&wt[(c0 + 16 + col) * 512 + ko];
        acc[0][0] = MFMA16(a0, b0, acc[0][0]);
        acc[0][1] = MFMA16(a0, b1, acc[0][1]);
        acc[1][0] = MFMA16(a1, b0, acc[1][0]);
        acc[1][1] = MFMA16(a1, b1, acc[1][1]);
    }
    const float qscale = (which == 0) ? 0.125f : 1.0f;  // fold SCALE into q
#pragma unroll
    for (int i = 0; i < 2; i++)
#pragma unroll
        for (int j = 0; j < 2; j++)
#pragma unroll
            for (int r = 0; r < 4; r++) {
                int il = (wv >> 1) * 32 + i * 16 + quad * 4 + r;
                int cl = (wv & 1) * 32 + j * 16 + col;
                ushort_t hv = f2bf(acc[i][j][r] * qscale);
                if (which == 2) st[cl * 72 + il] = hv;   // transposed: [d][n]
                else            st[il * 72 + cl] = hv;   // [n][d]
            }
    __syncthreads();
    if (which < 2) {
        ushort_t* dst = (which == 0) ? qs : ks;
#pragma unroll
        for (int s = tid; s < 512; s += 256) {
            int rr = s >> 3, dc = (s & 7) * 8;
            *(short8*)&dst[(hidx * 2048 + n0 + rr) * 64 + dc] = *(const short8*)&st[rr * 72 + dc];
        }
    } else {
#pragma unroll
        for (int s = tid; s < 512; s += 256) {
            int d = s >> 3, nc = (s & 7) * 8;
            *(short8*)&vt[(hidx * 64 + d) * 2048 + n0 + nc] = *(const short8*)&st[d * 72 + nc];
        }
    }
}

// ---------------------------------------------------------------- K2a: softmax denominators
// Streaming QK + premix + exp -> partial l_g[i]. min_waves=2: empirically 128-reg
// budget (the =4 cap of 64 regs caused 114 MB of spill writes in round 4).
__global__ __launch_bounds__(256, 2) void k_lsum(const ushort_t* __restrict__ qs,
                                                 const ushort_t* __restrict__ ks,
                                                 const float* __restrict__ w_pre,
                                                 float* __restrict__ lpart) {
    __shared__ float wpre_s[64];
    __shared__ __align__(16) ushort_t qlds[8 * 16 * 72];
    __shared__ float lredL[4][8][16];
    const int tid = threadIdx.x, lane = tid & 63, wv = tid >> 6;
    const int col = lane & 15, quad = lane >> 4;
    const int b = blockIdx.y, n0 = blockIdx.x * 16;
    const int jt = blockIdx.z * 4 + wv;  // this wave's 512-j slice -> 8 x 16-j chunks
    if (tid < 64) wpre_s[tid] = w_pre[tid];
    for (int c = tid; c < 1024; c += 256) {
        int hh = c >> 7, rem = c & 127, ii = rem >> 3, dc = (rem & 7) * 8;
        *(short8*)&qlds[(hh * 16 + ii) * 72 + dc] =
            *(const short8*)&qs[((b * 8 + hh) * 2048 + n0 + ii) * 64 + dc];
    }
    __syncthreads();

    floatx4 Lacc[8];
#pragma unroll
    for (int g = 0; g < 8; g++) Lacc[g] = (floatx4){0.f, 0.f, 0.f, 0.f};

    for (int jc = 0; jc < 8; jc++) {
        const int j0 = jt * 128 + jc * 16;
        floatx4 S[8];
#pragma unroll
        for (int h = 0; h < 8; h++) {
            const ushort_t* qb = &qlds[(h * 16 + col) * 72 + quad * 8];
            short8 a0 = *(const short8*)&qb[0];
            short8 a1 = *(const short8*)&qb[32];
            const ushort_t* kp = &ks[((b * 8 + h) * 2048 + j0 + col) * 64 + quad * 8];
            short8 b0 = *(const short8*)&kp[0];
            short8 b1 = *(const short8*)&kp[32];
            floatx4 a = (floatx4){0.f, 0.f, 0.f, 0.f};
            a = MFMA16(a0, b0, a);
            a = MFMA16(a1, b1, a);
            S[h] = a;
        }
#pragma unroll
        for (int g = 0; g < 8; g++) {
            floatx4 w0 = *(const floatx4*)&wpre_s[g * 8];
            floatx4 w1 = *(const floatx4*)&wpre_s[g * 8 + 4];
            floatx4 s4 = (floatx4){0.f, 0.f, 0.f, 0.f};
#pragma unroll
            for (int h = 0; h < 4; h++) s4 = fma4(w0[h], S[h], s4);
#pragma unroll
            for (int h = 0; h < 4; h++) s4 = fma4(w1[h], S[h + 4], s4);
            floatx4 u4;
            u4[0] = __expf(s4[0]);
            u4[1] = __expf(s4[1]);
            u4[2] = __expf(s4[2]);
            u4[3] = __expf(s4[3]);
            Lacc[g] += u4;
        }
    }
    // reduce over the 16 j-columns (lane&15), then across the block's 4 waves
#pragma unroll
    for (int g = 0; g < 8; g++)
#pragma unroll
        for (int r = 0; r < 4; r++) {
            float v = Lacc[g][r];
            v += __shfl_xor(v, 1, 64);
            v += __shfl_xor(v, 2, 64);
            v += __shfl_xor(v, 4, 64);
            v += __shfl_xor(v, 8, 64);
            if (col == 0) lredL[wv][g][quad * 4 + r] = v;
        }
    __syncthreads();
    if (tid < 128) {
        int g = tid >> 4, ii = tid & 15;
        float s = lredL[0][g][ii] + lredL[1][g][ii] + lredL[2][g][ii] + lredL[3][g][ii];
        lpart[(blockIdx.z * 16 + b * 8 + g) * 2048 + n0 + ii] = s;
    }
}

// ---------------------------------------------------------------- K2b: normalized+mixed attn, PV
// j-split 2 -> grid 512, LDS 54 KB -> 2 blocks/CU by LDS. min_waves=2 for the
// 128-reg budget (the =4 cap of 64 regs spilled 771 MB in round 3); inline K/V
// loads, TLP hides latency. Two lgkm-only barriers per tile.
__global__ __launch_bounds__(512, 2) void k_attn(const ushort_t* __restrict__ qs,
                                                 const ushort_t* __restrict__ ks,
                                                 const ushort_t* __restrict__ vt,
                                                 const float* __restrict__ w_pre,
                                                 const float* __restrict__ w_post,
                                                 const float* __restrict__ lpart,
                                                 float* __restrict__ opart) {
    __shared__ __align__(16) ushort_t qlds[8 * 16 * 72];  // q tiles, 8 heads x 16 rows
    __shared__ __align__(16) ushort_t A[8 * 16 * 136];    // mixed attn (single buffer)
    __shared__ __align__(16) float wbuf[128];             // fp32 w_pre | w_post
    __shared__ __align__(16) float linv_s[8][16];         // 1 / l_g[i]
    const int tid = threadIdx.x, lane = tid & 63, wv = tid >> 6;
    const int col = lane & 15, quad = lane >> 4;
    const int b = blockIdx.y, n0 = blockIdx.x * 16;
    const int jb = blockIdx.z * 8;  // this block's jt range [jb, jb+8)
    const int e = wv;               // wave's output head

    if (tid < 64) wbuf[tid] = w_pre[tid];
    else if (tid < 128) wbuf[tid] = w_post[tid - 64];
    if (tid < 128) {  // 1/l from the 4 partial slices
        int g = tid >> 4, ii = tid & 15;
        float l = 0.f;
#pragma unroll
        for (int p = 0; p < 4; p++) l += lpart[(p * 16 + b * 8 + g) * 2048 + n0 + ii];
        linv_s[g][ii] = 1.0f / l;
    }
    for (int c = tid; c < 1024; c += 512) {
        int hh = c >> 7, rem = c & 127, ii = rem >> 3, dc = (rem & 7) * 8;
        *(short8*)&qlds[(hh * 16 + ii) * 72 + dc] =
            *(const short8*)&qs[((b * 8 + hh) * 2048 + n0 + ii) * 64 + dc];
    }
    floatx4 Oa[4];
#pragma unroll
    for (int nt = 0; nt < 4; nt++) Oa[nt] = (floatx4){0.f, 0.f, 0.f, 0.f};
    __syncthreads();  // qlds + wbuf + linv visible

    for (int t = 0; t < 8; t++) {
        const int jt = jb + t;
        // ---- QK for 8 heads; K loaded inline (no persistent arrays)
        floatx4 S[8];
#pragma unroll
        for (int h = 0; h < 8; h++) {
            const ushort_t* qb = &qlds[(h * 16 + col) * 72 + quad * 8];
            short8 a0 = *(const short8*)&qb[0];
            short8 a1 = *(const short8*)&qb[32];
            const ushort_t* kp = &ks[((b * 8 + h) * 2048 + jt * 128 + wv * 16 + col) * 64 +
                                     quad * 8];
            short8 b0 = *(const short8*)&kp[0];
            short8 b1 = *(const short8*)&kp[32];
            floatx4 a = (floatx4){0.f, 0.f, 0.f, 0.f};
            a = MFMA16(a0, b0, a);
            a = MFMA16(a1, b1, a);
            S[h] = a;
        }
        // ---- premix + exp + normalize -> Ug
        floatx4 Ug[8];
#pragma unroll
        for (int g = 0; g < 8; g++) {
            floatx4 w0 = *(const floatx4*)&wbuf[g * 8];
            floatx4 w1 = *(const floatx4*)&wbuf[g * 8 + 4];
            floatx4 s4 = (floatx4){0.f, 0.f, 0.f, 0.f};
#pragma unroll
            for (int h = 0; h < 4; h++) s4 = fma4(w0[h], S[h], s4);
#pragma unroll
            for (int h = 0; h < 4; h++) s4 = fma4(w1[h], S[h + 4], s4);
            floatx4 lg = *(const floatx4*)&linv_s[g][quad * 4];
            floatx4 u4;
            u4[0] = __expf(s4[0]) * lg[0];
            u4[1] = __expf(s4[1]) * lg[1];
            u4[2] = __expf(s4[2]) * lg[2];
            u4[3] = __expf(s4[3]) * lg[3];
            Ug[g] = u4;
        }
        // ---- barrier 1: all waves' PV reads of A (prev tile) complete
        asm volatile("s_waitcnt lgkmcnt(0)\n\ts_barrier" ::: "memory");
        // ---- post-mix: A_e = sum_g w_post[e,g] * Ug -> LDS (A-operand layout)
#pragma unroll
        for (int e2 = 0; e2 < 8; e2++) {
            floatx4 wqa = *(const floatx4*)&wbuf[64 + e2 * 8];
            floatx4 wqb = *(const floatx4*)&wbuf[64 + e2 * 8 + 4];
            floatx4 a4 = (floatx4){0.f, 0.f, 0.f, 0.f};
#pragma unroll
            for (int g = 0; g < 4; g++) a4 = fma4(wqa[g], Ug[g], a4);
#pragma unroll
            for (int g = 0; g < 4; g++) a4 = fma4(wqb[g], Ug[g + 4], a4);
#pragma unroll
            for (int r = 0; r < 4; r++)
                A[(e2 * 16 + quad * 4 + r) * 136 + wv * 16 + col] = f2bf(a4[r]);
        }
        // ---- barrier 2: A writes visible
        asm volatile("s_waitcnt lgkmcnt(0)\n\ts_barrier" ::: "memory");
        // ---- PV: O_e += A_e @ V_e; V loaded inline
#pragma unroll
        for (int k2 = 0; k2 < 4; k2++) {
            short8 af = *(const short8*)&A[(e * 16 + col) * 136 + k2 * 32 + quad * 8];
#pragma unroll
            for (int nt = 0; nt < 4; nt++) {
                short8 bv = *(const short8*)&vt[((b * 8 + e) * 64 + nt * 16 + col) * 2048 +
                                                jt * 128 + k2 * 32 + quad * 8];
                Oa[nt] = MFMA16(af, bv, Oa[nt]);
            }
        }
    }

    // ---- epilogue: fp32 partial O-hat for this j-half
#pragma unroll
    for (int nt = 0; nt < 4; nt++)
#pragma unroll
        for (int r = 0; r < 4; r++)
            opart[((blockIdx.z * 2 + b) * 2048 + n0 + quad * 4 + r) * 512 + e * 64 + nt * 16 +
                  col] = Oa[nt][r];
}

// ---------------------------------------------------------------- K3: combine halves + out proj
__global__ __launch_bounds__(256) void k_proj(const float* __restrict__ opart,
                                              const ushort_t* __restrict__ wot,
                                              const float* __restrict__ bias,
                                              float* __restrict__ out) {
    __shared__ __align__(16) ushort_t oline[16 * 520];
    const int tid = threadIdx.x, lane = tid & 63, wv = tid >> 6;
    const int col = lane & 15, quad = lane >> 4;
    const int b = blockIdx.y, n0 = blockIdx.x * 16;
#pragma unroll
    for (int it = 0; it < 8; it++) {
        int idx = it * 256 + tid;
        int row = idx >> 7, c4 = (idx & 127) << 2;
        floatx4 v0 = *(const floatx4*)&opart[((0 + b) * 2048 + n0 + row) * 512 + c4];
        floatx4 v1 = *(const floatx4*)&opart[((2 + b) * 2048 + n0 + row) * 512 + c4];
        floatx4 s = v0 + v1;
        short4v o;
        o[0] = (short)f2bf(s[0]);
        o[1] = (short)f2bf(s[1]);
        o[2] = (short)f2bf(s[2]);
        o[3] = (short)f2bf(s[3]);
        *(short4v*)&oline[row * 520 + c4] = o;
    }
    __syncthreads();
#pragma unroll
    for (int ct = 0; ct < 4; ct++) {
        floatx4 acc = (floatx4){0.f, 0.f, 0.f, 0.f};
        const int c = blockIdx.z * 256 + wv * 64 + ct * 16 + col;
#pragma unroll
        for (int k2 = 0; k2 < 16; k2++) {
            short8 af = *(const short8*)&oline[col * 520 + k2 * 32 + quad * 8];
            short8 bf = *(const short8*)&wot[c * 512 + k2 * 32 + quad * 8];
            acc = MFMA16(af, bf, acc);
        }
        float bz = bias[c];
#pragma unroll
        for (int r = 0; r < 4; r++)
            out[(b * 2048 + n0 + quad * 4 + r) * 512 + c] = acc[r] + bz;
    }
}

// ---------------------------------------------------------------- launch
extern "C" void kernel_launch(void* const* d_in, const int* in_sizes, int n_in,
                              void* d_out, int out_size, void* d_ws, size_t ws_size,
                              hipStream_t stream) {
    const float* x = (const float*)d_in[0];
    const float* w_qkv = (const float*)d_in[1];
    const float* w_pre = (const float*)d_in[2];
    const float* w_post = (const float*)d_in[3];
    const float* w_out = (const float*)d_in[4];
    const float* b_out = (const float*)d_in[5];
    char* ws = (char*)d_ws;
    ushort_t* qs = (ushort_t*)(ws);                            // 4 MB   [b,h,n,d] (pre-scaled)
    ushort_t* ks = (ushort_t*)(ws + (4u << 20));               // 4 MB   [b,h,n,d]
    ushort_t* vt = (ushort_t*)(ws + (8u << 20));               // 4 MB   [b,h,d,n]
    ushort_t* xb = (ushort_t*)(ws + (12u << 20));              // 4 MB   x in bf16
    ushort_t* wt = (ushort_t*)(ws + (16u << 20));              // 1.5 MB w_qkv^T bf16
    ushort_t* wot = (ushort_t*)(ws + (16u << 20) + 1572864u);  // 0.5 MB w_out^T bf16
    float* lpart = (float*)(ws + (18u << 20));                 // 0.5 MB 4 partial l slices
    float* opart = (float*)(ws + (19u << 20));                 // 16 MB  2 partial O-hat (fp32)
    float* out = (float*)d_out;

    k_cvt<<<dim3(2048), dim3(256), 0, stream>>>((const floatx4*)x, (short4v*)xb, 524288);
    k_transpose_cvt<<<dim3(48, 16), dim3(256), 0, stream>>>(w_qkv, wt, 512, 1536);
    k_transpose_cvt<<<dim3(16, 16), dim3(256), 0, stream>>>(w_out, wot, 512, 512);
    k_qkv<<<dim3(24, 64), dim3(256), 0, stream>>>(xb, wt, qs, ks, vt);
    k_lsum<<<dim3(128, 2, 4), dim3(256), 0, stream>>>(qs, ks, w_pre, lpart);
    k_attn<<<dim3(128, 2, 2), dim3(512), 0, stream>>>(qs, ks, vt, w_pre, w_post, lpart, opart);
    k_proj<<<dim3(128, 2, 2), dim3(256), 0, stream>>>(opart, wot, b_out, out);
}